// Round 2
// baseline (344.859 us; speedup 1.0000x reference)
//
#include <hip/hip_runtime.h>
#include <hip/hip_bf16.h>

// Problem: Conv2dKan. b=16, cin=cout=64, H=W=32, K=3, PAD=1, BASIS=8 (Chebyshev of tanh).
// Inputs/outputs are float32 (per reference). Internals: Aact bf16, W3/accum fp32.
// out[b,o,l] = bias[o] + sum_{i,k} dot8( W3[i,k,o,:], A[b,i,pix(l,k),:] )
//   W3[...,0]=w, W3[...,1..7]=w*c[s];  A[...,:]=[silu(x), T1(tanh x)..T7(tanh x)]
//   bias[o] = sum_{i,k} w[i,o,k]*c[i,o,k,0]   (T0==1, input-independent)
// Padding cells use the activation of x=0: [0,0,-1,0,1,0,-1,0].

#define CIN   64
#define COUT  64
#define HW    32
#define LL    1024   // 32*32
#define NS    8

// ws layout (bytes):
//   [0)        W3   : 64*9*64*8 f32    = 1179648 B
//   [1179648)  bias : 64 f32           = 256 B
//   [1179904)  Aact : 16*64*1024*8 bf16 = 16777216 B   (16-byte aligned)
//   total ~18 MB

__global__ void prep_w_kernel(const float* __restrict__ w,
                              const float* __restrict__ c,
                              float* __restrict__ W3) {
    int tid = blockIdx.x * 256 + threadIdx.x;
    if (tid >= CIN * 9 * COUT) return;
    int i = tid / (9 * COUT);
    int r = tid - i * 9 * COUT;
    int k = r / COUT;
    int o = r - k * COUT;
    int widx = (i * COUT + o) * 9 + k;
    float wv = w[widx];
    float* dst = W3 + ((i * 9 + k) * COUT + o) * NS;
    dst[0] = wv;
#pragma unroll
    for (int s = 1; s < 8; ++s) dst[s] = wv * c[widx * 8 + s];
}

__global__ void prep_bias_kernel(const float* __restrict__ w,
                                 const float* __restrict__ c,
                                 float* __restrict__ bias) {
    int o = threadIdx.x;  // 64 threads
    float acc = 0.f;
    for (int i = 0; i < CIN; ++i) {
#pragma unroll
        for (int k = 0; k < 9; ++k) {
            int idx = (i * COUT + o) * 9 + k;
            acc += w[idx] * c[idx * 8];
        }
    }
    bias[o] = acc;
}

__global__ void act_kernel(const float* __restrict__ x,
                           __hip_bfloat16* __restrict__ Aact) {
    int idx = blockIdx.x * 256 + threadIdx.x;  // 1,048,576 = b*cin*h*w
    float xv = x[idx];
    float sig = 1.f / (1.f + __expf(-xv));
    float res = xv * sig;
    float t  = tanhf(xv);
    float T2 = 2.f * t * t  - 1.f;
    float T3 = 2.f * t * T2 - t;
    float T4 = 2.f * t * T3 - T2;
    float T5 = 2.f * t * T4 - T3;
    float T6 = 2.f * t * T5 - T4;
    float T7 = 2.f * t * T6 - T5;
    __align__(16) __hip_bfloat16 hv[8];
    hv[0] = __float2bfloat16(res);
    hv[1] = __float2bfloat16(t);
    hv[2] = __float2bfloat16(T2);
    hv[3] = __float2bfloat16(T3);
    hv[4] = __float2bfloat16(T4);
    hv[5] = __float2bfloat16(T5);
    hv[6] = __float2bfloat16(T6);
    hv[7] = __float2bfloat16(T7);
    *(float4*)(Aact + (size_t)idx * NS) = *(const float4*)hv;
}

// d_out is re-poisoned before every launch -> must write bias every call.
__global__ void init_out_kernel(const float* __restrict__ bias,
                                float* __restrict__ out) {
    int idx = blockIdx.x * 256 + threadIdx.x;  // 1,048,576  (b,o,l)
    out[idx] = bias[(idx >> 10) & 63];
}

// Grid: x = o-chunk (4 of 16), y = row tile (4 of 8 rows), z = b*4 + i-group(16ch).
__global__ __launch_bounds__(256) void kan_main_kernel(const float* __restrict__ W3,
                                                       const __hip_bfloat16* __restrict__ Aact,
                                                       float* __restrict__ out) {
    __shared__ float4 lds4[340];  // 10 rows x 34 cols, 8 bf16 each = 16B/cell
    const int o0 = blockIdx.x * 16;
    const int y0 = blockIdx.y * 8;
    const int b  = blockIdx.z >> 2;
    const int ig = blockIdx.z & 3;
    const int tid = threadIdx.x;
    const int ry = tid >> 5;   // 0..7
    const int cx = tid & 31;   // 0..31

    float acc[16];
#pragma unroll
    for (int j = 0; j < 16; ++j) acc[j] = 0.f;

    for (int ii = 0; ii < 16; ++ii) {
        const int i = ig * 16 + ii;
        const __hip_bfloat16* Ab = Aact + (size_t)(b * CIN + i) * LL * NS;
        __syncthreads();  // previous iteration's readers done before overwrite
        for (int j = tid; j < 340; j += 256) {
            int r  = j / 34;
            int cc = j - r * 34;
            int y  = y0 - 1 + r;
            int xg = cc - 1;
            float4 v;
            if ((unsigned)y < 32u && (unsigned)xg < 32u) {
                v = *(const float4*)(Ab + (y * HW + xg) * NS);
            } else {
                // activation vector of x=0: [silu=0, T1=0, T2=-1, T3=0, T4=1, T5=0, T6=-1, T7=0]
                union { unsigned int u[4]; float4 f; } Z;
                Z.u[0] = 0x00000000u;  // (0, 0)
                Z.u[1] = 0x0000BF80u;  // (-1, 0)
                Z.u[2] = 0x00003F80u;  // (1, 0)
                Z.u[3] = 0x0000BF80u;  // (-1, 0)
                v = Z.f;
            }
            lds4[j] = v;
        }
        __syncthreads();

#pragma unroll
        for (int dy = 0; dy < 3; ++dy) {
#pragma unroll
            for (int dx = 0; dx < 3; ++dx) {
                const int k = dy * 3 + dx;
                union { float4 f; unsigned int u[4]; } U;
                U.f = lds4[(ry + dy) * 34 + (cx + dx)];
                float a[8];
#pragma unroll
                for (int j = 0; j < 4; ++j) {
                    a[2 * j]     = __uint_as_float(U.u[j] << 16);
                    a[2 * j + 1] = __uint_as_float(U.u[j] & 0xffff0000u);
                }
                // wave-uniform weight pointer -> scalar loads
                const float* wp = W3 + ((i * 9 + k) * COUT + o0) * NS;
#pragma unroll
                for (int oo = 0; oo < 16; ++oo) {
                    const float* wo = wp + oo * NS;
                    float s = acc[oo];
#pragma unroll
                    for (int q = 0; q < 8; ++q) s = fmaf(wo[q], a[q], s);
                    acc[oo] = s;
                }
            }
        }
    }

    const int l = (y0 + ry) * HW + cx;
    float* op = out + (size_t)(b * COUT + o0) * LL + l;
#pragma unroll
    for (int oo = 0; oo < 16; ++oo) atomicAdd(op + oo * LL, acc[oo]);
}

extern "C" void kernel_launch(void* const* d_in, const int* in_sizes, int n_in,
                              void* d_out, int out_size, void* d_ws, size_t ws_size,
                              hipStream_t stream) {
    const float* x = (const float*)d_in[0];
    const float* w = (const float*)d_in[1];
    const float* c = (const float*)d_in[2];
    float* out = (float*)d_out;

    char* ws = (char*)d_ws;
    float* W3     = (float*)(ws);
    float* bias   = (float*)(ws + 1179648);
    __hip_bfloat16* Aact = (__hip_bfloat16*)(ws + 1179904);

    prep_w_kernel<<<144, 256, 0, stream>>>(w, c, W3);
    prep_bias_kernel<<<1, 64, 0, stream>>>(w, c, bias);
    act_kernel<<<4096, 256, 0, stream>>>(x, Aact);
    init_out_kernel<<<4096, 256, 0, stream>>>(bias, out);
    kan_main_kernel<<<dim3(4, 4, 64), 256, 0, stream>>>(W3, Aact, out);
}

// Round 3
// 93.682 us; speedup vs baseline: 3.6812x; 3.6812x over previous
//
#include <hip/hip_runtime.h>
#include <hip/hip_bf16.h>

// Conv2dKan via implicit-GEMM MFMA. b=16, cin=cout=64, H=W=32, K=3, PAD=1, BASIS=8.
// out[b,o,pix] = bias[o] + sum_{i,k,s8} Wt[i,k,o,s]*Ah[b,i,pix+off(k),s]
//   Wt[...,0]=w, Wt[...,s]=w*c[s] (s=1..7), bf16
//   Ah = [silu(x), T1..T7(tanh x)] on a 34x34 halo grid; border = act(0) = [0,0,-1,0,1,0,-1,0]
//   bias[o] = sum_{i,k} w*c[...,0]  (T0==1)
// MFMA 16x16x32 bf16, A-operand = weights (M=o), B-operand = activations (N=pix)
// -> D rows=o, cols=pix -> coalesced fp32 stores, no atomics, no split-K.

#define CIN   64
#define COUT  64
#define HW    32
#define LL    1024
#define NS    8
#define AH    34          // halo grid dim
#define AHC   1156        // 34*34 cells per (b,i)

typedef __attribute__((ext_vector_type(8))) short short8;
typedef __attribute__((ext_vector_type(4))) float f32x4;

// ws layout (bytes):
//   [0)       Wt   : 64*9*64*8 bf16 = 589824 B   ([i][k][o][s])
//   [589824)  bias : 64 f32         = 256 B
//   [590080)  Ah   : 16*64*1156*8 bf16 = 18939904 B
//   total ~19.5 MB

__global__ void prep_w_kernel(const float* __restrict__ w,
                              const float* __restrict__ c,
                              __hip_bfloat16* __restrict__ Wt) {
    int tid = blockIdx.x * 256 + threadIdx.x;   // 36864 = 64i*9k*64o
    if (tid >= CIN * 9 * COUT) return;
    int i = tid / (9 * COUT);
    int r = tid - i * 9 * COUT;
    int k = r / COUT;
    int o = r - k * COUT;
    int widx = (i * COUT + o) * 9 + k;
    float wv = w[widx];
    __hip_bfloat16* dst = Wt + (size_t)tid * NS;   // tid == (i*9+k)*64+o
    dst[0] = __float2bfloat16(wv);
#pragma unroll
    for (int s = 1; s < 8; ++s) dst[s] = __float2bfloat16(wv * c[widx * 8 + s]);
}

__global__ void prep_bias_kernel(const float* __restrict__ w,
                                 const float* __restrict__ c,
                                 float* __restrict__ bias) {
    int o = blockIdx.x;      // 64 blocks
    int i = threadIdx.x;     // 64 threads = 1 wave
    float v = 0.f;
#pragma unroll
    for (int k = 0; k < 9; ++k) {
        int idx = (i * COUT + o) * 9 + k;
        v += w[idx] * c[idx * 8];
    }
#pragma unroll
    for (int off = 32; off > 0; off >>= 1) v += __shfl_down(v, off);
    if (i == 0) bias[o] = v;
}

__global__ void act_kernel(const float* __restrict__ x,
                           __hip_bfloat16* __restrict__ Ah) {
    int idx = blockIdx.x * 256 + threadIdx.x;   // 1,183,744 = 16*64*1156
    int bi = idx / AHC;
    int r  = idx - bi * AHC;
    int yy = r / AH;
    int xx = r - yy * AH;
    __align__(16) __hip_bfloat16 hv[8];
    if (yy >= 1 && yy <= 32 && xx >= 1 && xx <= 32) {
        float xv = x[bi * LL + (yy - 1) * HW + (xx - 1)];
        float e  = __expf(-xv);
        float res = xv / (1.f + e);              // silu
        float e2 = __expf(2.f * xv);
        float t  = 1.f - 2.f / (e2 + 1.f);       // tanh
        float T2 = 2.f * t * t  - 1.f;
        float T3 = 2.f * t * T2 - t;
        float T4 = 2.f * t * T3 - T2;
        float T5 = 2.f * t * T4 - T3;
        float T6 = 2.f * t * T5 - T4;
        float T7 = 2.f * t * T6 - T5;
        hv[0] = __float2bfloat16(res); hv[1] = __float2bfloat16(t);
        hv[2] = __float2bfloat16(T2);  hv[3] = __float2bfloat16(T3);
        hv[4] = __float2bfloat16(T4);  hv[5] = __float2bfloat16(T5);
        hv[6] = __float2bfloat16(T6);  hv[7] = __float2bfloat16(T7);
    } else {
        // activation of x=0: [0, 0, -1, 0, 1, 0, -1, 0]
        union { unsigned int u[4]; } Z;
        ((unsigned int*)hv)[0] = 0x00000000u;
        ((unsigned int*)hv)[1] = 0x0000BF80u;
        ((unsigned int*)hv)[2] = 0x00003F80u;
        ((unsigned int*)hv)[3] = 0x0000BF80u;
    }
    *(float4*)(Ah + (size_t)idx * NS) = *(const float4*)hv;
}

// grid (16 row-pairs, 16 batches), block 256 (4 waves).
// Tile: M=64 pixels (rows y0,y0+1), N=64 outputs, full K=4608 -> direct store.
__global__ __launch_bounds__(256) void kan_mfma_kernel(
        const __hip_bfloat16* __restrict__ Wt,
        const float* __restrict__ bias,
        const __hip_bfloat16* __restrict__ Ah,
        float* __restrict__ out) {
    // one 8-channel weight chunk: 8i * 9k * 64o * 8s bf16 = 73728 B
    __shared__ __align__(16) unsigned short Wlds[36864];

    const int tid  = threadIdx.x;
    const int wv   = tid >> 6;        // wave 0..3
    const int lane = tid & 63;
    const int quad = lane >> 4;       // 0..3  (i-offset within MFMA K)
    const int l16  = lane & 15;

    const int rp = blockIdx.x;        // row pair
    const int b  = blockIdx.y;
    const int y0 = rp * 2;

    // B-operand (activations): pixel = (y0 + (wv>>1))*32 + (wv&1)*16 + l16, channel quad
    const int py = y0 + (wv >> 1);
    const int px = ((wv & 1) << 4) + l16;
    const unsigned short* ap0 = (const unsigned short*)Ah +
        (((size_t)(b * CIN + quad)) * AHC + (py + 1) * AH + (px + 1)) * NS;

    // A-operand (weights) LDS lane base (ushort units): [i_in][k][o][s]
    // elem = ((i_in*9 + k)*64 + o)*8 ; lane part: i_in = istep*4+quad, o = nt*16+l16
    f32x4 acc[4];
#pragma unroll
    for (int nt = 0; nt < 4; ++nt) acc[nt] = (f32x4){0.f, 0.f, 0.f, 0.f};

    for (int ig = 0; ig < 8; ++ig) {
        __syncthreads();
        {   // stage 73728 B = 4608 float4, 18 passes
            const float4* src = (const float4*)(Wt + (size_t)ig * 8 * 9 * COUT * NS);
            float4* dst = (float4*)Wlds;
#pragma unroll
            for (int p = 0; p < 18; ++p) dst[p * 256 + tid] = src[p * 256 + tid];
        }
        __syncthreads();

#pragma unroll
        for (int istep = 0; istep < 2; ++istep) {
            const unsigned short* ap = ap0 + (size_t)(ig * 8 + istep * 4) * AHC * NS;
            const unsigned short* wbase = Wlds + ((istep * 4 + quad) * 9 * 64 + l16) * NS;
#pragma unroll
            for (int k = 0; k < 9; ++k) {
                const int dy = k / 3 - 1, dx = k % 3 - 1;
                short8 af = *(const short8*)(ap + (dy * AH + dx) * NS);
#pragma unroll
                for (int nt = 0; nt < 4; ++nt) {
                    short8 wf = *(const short8*)(wbase + (k * 64 + nt * 16) * NS);
                    acc[nt] = __builtin_amdgcn_mfma_f32_16x16x32_bf16(wf, af, acc[nt], 0, 0, 0);
                }
            }
        }
    }

    // D: row = o_local = quad*4+r, col = pixel = l16
    const int pix = py * HW + ((wv & 1) << 4) + l16;
#pragma unroll
    for (int nt = 0; nt < 4; ++nt) {
#pragma unroll
        for (int r = 0; r < 4; ++r) {
            const int o = nt * 16 + quad * 4 + r;
            out[((size_t)(b * COUT + o)) * LL + pix] = acc[nt][r] + bias[o];
        }
    }
}

extern "C" void kernel_launch(void* const* d_in, const int* in_sizes, int n_in,
                              void* d_out, int out_size, void* d_ws, size_t ws_size,
                              hipStream_t stream) {
    const float* x = (const float*)d_in[0];
    const float* w = (const float*)d_in[1];
    const float* c = (const float*)d_in[2];
    float* out = (float*)d_out;

    char* ws = (char*)d_ws;
    __hip_bfloat16* Wt   = (__hip_bfloat16*)(ws);
    float*          bias = (float*)(ws + 589824);
    __hip_bfloat16* Ah   = (__hip_bfloat16*)(ws + 590080);

    prep_w_kernel<<<144, 256, 0, stream>>>(w, c, Wt);
    prep_bias_kernel<<<64, 64, 0, stream>>>(w, c, bias);
    act_kernel<<<4624, 256, 0, stream>>>(x, Ah);
    kan_mfma_kernel<<<dim3(16, 16), 256, 0, stream>>>(Wt, bias, Ah, out);
}